// Round 3
// baseline (50.399 us; speedup 1.0000x reference)
//
#include <hip/hip_runtime.h>

typedef unsigned short u16;
typedef _Float16 f16x2 __attribute__((ext_vector_type(2)));
typedef _Float16 f16x8 __attribute__((ext_vector_type(8)));
typedef float    f32x4  __attribute__((ext_vector_type(4)));
typedef float    f32x16 __attribute__((ext_vector_type(16)));

// Fragment k-map convention (same for A and B operands, so any within-lane
// permutation cancels in the MFMA contraction):
//   k_local(lane, j) = (lane>>5)*4 + (j&3) + 8*(j>>2),  j = 0..7
// D layout (measured m74/m101): col = lane&31, row = (r&3) + 8*(r>>2) + 4*(lane>>5)

union U4 { uint4 u; f16x8 h; u16 s[8]; };
union HU { f16x2 h2[4]; f16x8 h8; };

// ---------------------------------------------------------------------------
// Prep kernel (unchanged, proven): W2flat (2080 x 32, f16) + W1 (16 x 64, f16)
// in MFMA B-fragment order into d_ws.
//   W2flat[kk][i] = kk < 2048 ? W2[kk>>5][i*32 + (kk&31)] : b2[i*32 + kk-2048]
//   Bf slot (k2, lane): 8 f16 at ws + (k2*64 + lane)*8,  kk = k2*16 + k_local
//   W1f slot (nt, lane): at ws + (8320 + nt*64 + lane)*8
// ---------------------------------------------------------------------------
__global__ void prep_kernel(const float* __restrict__ W1,
                            const float* __restrict__ W2,
                            const float* __restrict__ b2,
                            u16* __restrict__ ws)
{
    int id = blockIdx.x * 256 + threadIdx.x;
    if (id < 8320) {                       // 130 ksteps * 64 lanes
        int k2 = id >> 6, l = id & 63;
        int h = l >> 5, col = l & 31;
        U4 o;
        #pragma unroll
        for (int g = 0; g < 2; ++g) {
            int base4 = k2 * 16 + g * 8 + h * 4;   // 4-aligned, no 32-straddle
            f32x4 v;
            if (base4 < 2048) {
                int k1 = base4 >> 5, j32 = base4 & 31;
                v = *(const f32x4*)&W2[k1 * 1024 + col * 32 + j32];
            } else {
                v = *(const f32x4*)&b2[col * 32 + (base4 - 2048)];
            }
            #pragma unroll
            for (int j = 0; j < 4; ++j)
                o.h[g * 4 + j] = (_Float16)v[j];
        }
        *(uint4*)(ws + id * 8) = o.u;
    } else if (id < 8448) {                // W1 fragments: 2 ntiles * 64 lanes
        int idx = id - 8320;
        int nt = idx >> 6, l = idx & 63;
        int h = l >> 5, col = nt * 32 + (l & 31);
        U4 o;
        #pragma unroll
        for (int g = 0; g < 2; ++g)
            #pragma unroll
            for (int j = 0; j < 4; ++j) {
                int k = g * 8 + h * 4 + j;
                o.h[g * 4 + j] = (_Float16)W1[k * 64 + col];
            }
        *(uint4*)(ws + id * 8) = o.u;
    }
}

// ---------------------------------------------------------------------------
// Main kernel: 4 waves/block, 64 edges/wave. B-fragments staged through LDS
// with 2-phase global_load_lds double-buffer (chunk = 4 k1 = 8 KB):
//   STAGE(c+1) -> COMPUTE(c) from LDS -> __syncthreads()   (T3-minimum)
// Inner loop is LDS-only (ds_read_b128 B + ds_read_u16 hdnT); the ~300-cyc
// L2 latency of staging hides under ~530 cyc of MFMA per chunk.
// LDS: 16 KB B-dbuf + 34.8 KB hdnT = 51.2 KB -> 3 blocks/CU.
// NO early returns (all waves hit every barrier).
// ---------------------------------------------------------------------------
#define STRIDE_T 66
#define SLICE_T  4352   // u16 per wave (need 64*66+64 = 4288)
#define B_U16    8192   // 16384 bytes = double-buffered 8 KB chunks

__device__ __forceinline__ void stage16(const void* g, void* l) {
    __builtin_amdgcn_global_load_lds(
        (const __attribute__((address_space(1))) void*)g,
        (__attribute__((address_space(3))) void*)l, 16, 0, 0);
}

#define MT_BODY(accv, hh, hwv, B0, B1) do {                                   \
    HU A_;                                                                    \
    A_.h2[0] = hh * hwv[0][0]; A_.h2[1] = hh * hwv[0][1];                     \
    A_.h2[2] = hh * hwv[0][2]; A_.h2[3] = hh * hwv[0][3];                     \
    accv = __builtin_amdgcn_mfma_f32_32x32x16_f16(A_.h8, B0, accv, 0, 0, 0);  \
    A_.h2[0] = hh * hwv[1][0]; A_.h2[1] = hh * hwv[1][1];                     \
    A_.h2[2] = hh * hwv[1][2]; A_.h2[3] = hh * hwv[1][3];                     \
    accv = __builtin_amdgcn_mfma_f32_32x32x16_f16(A_.h8, B1, accv, 0, 0, 0);  \
} while (0)

__global__ __launch_bounds__(256, 3) void edge_kernel(
    const float* __restrict__ h_w,
    const float* __restrict__ ef,
    const float* __restrict__ b1,
    const u16*  __restrict__ ws,
    float* __restrict__ out,
    int E)
{
    __shared__ alignas(16) u16 shm[B_U16 + 4 * SLICE_T];   // 51,200 B
    const int tid  = threadIdx.x;
    const int lane = tid & 63;
    const int wv   = tid >> 6;
    const int l31  = lane & 31;
    const int h    = lane >> 5;
    const int tileBase = (blockIdx.x * 4 + wv) * 64;
    u16* myT = shm + B_U16 + wv * SLICE_T;
    const char* wsb = (const char*)ws;
    char*       shb = (char*)shm;

    // ---- stage chunk 0 -> buf0 (DMA starts; layer-1 runs underneath) ----
    {
        int off = wv * 2048;
        stage16(wsb + off + lane * 16,        shb + off);
        stage16(wsb + off + 1024 + lane * 16, shb + off + 1024);
    }

    const uint4* W1f = (const uint4*)(ws + 8320 * 8);

    // ---------------- layer 1: hdn = relu(ef @ W1 + b1) ----------------
    U4 w0, w1;
    w0.u = W1f[lane];
    w1.u = W1f[64 + lane];
    const float bb0 = b1[l31], bb1 = b1[32 + l31];
    #pragma unroll
    for (int mt = 0; mt < 2; ++mt) {
        int e = tileBase + mt * 32 + l31;
        bool ok = e < E;
        f32x4 g0 = {}, g1 = {};
        if (ok) {
            g0 = *(const f32x4*)&ef[e * 16 + h * 4];
            g1 = *(const f32x4*)&ef[e * 16 + 8 + h * 4];
        }
        U4 a;
        #pragma unroll
        for (int j = 0; j < 4; ++j) {
            a.h[j]     = (_Float16)g0[j];
            a.h[4 + j] = (_Float16)g1[j];
        }
        f32x16 c0 = {}, c1 = {};
        c0 = __builtin_amdgcn_mfma_f32_32x32x16_f16(a.h, w0.h, c0, 0, 0, 0);
        c1 = __builtin_amdgcn_mfma_f32_32x32x16_f16(a.h, w1.h, c1, 0, 0, 0);
        // relu + bias, pack edge-pairs, transposed write hdnT[k1][e_local]
        #pragma unroll
        for (int nt = 0; nt < 2; ++nt) {
            float bb = nt ? bb1 : bb0;
            int k1 = nt * 32 + l31;
            #pragma unroll
            for (int rp = 0; rp < 8; ++rp) {
                int r = 2 * rp;
                float v0 = fmaxf((nt ? c1[r]     : c0[r])     + bb, 0.f);
                float v1 = fmaxf((nt ? c1[r + 1] : c0[r + 1]) + bb, 0.f);
                f16x2 p = { (_Float16)v0, (_Float16)v1 };
                int e0 = mt * 32 + (r & 3) + 8 * (r >> 2) + 4 * h; // even
                *(unsigned int*)(myT + k1 * STRIDE_T + e0) =
                    __builtin_bit_cast(unsigned int, p);
            }
        }
    }
    // bias row k1 = 64: hdn = 1.0 (feeds the b2 rows of W2flat)
    if (lane < 32)
        *(unsigned int*)(myT + 64 * STRIDE_T + lane * 2) = 0x3C003C00u;

    // ---------------- load h_w fragments (f16, kept in regs) ----------------
    f16x2 hwA[2][2][4];
    #pragma unroll
    for (int mt = 0; mt < 2; ++mt) {
        int e = tileBase + mt * 32 + l31;
        bool ok = e < E;
        f32x4 q0 = {}, q1 = {}, q2 = {}, q3 = {};
        if (ok) {
            const float* hp = h_w + (size_t)e * 32 + h * 4;
            q0 = *(const f32x4*)(hp);
            q1 = *(const f32x4*)(hp + 8);
            q2 = *(const f32x4*)(hp + 16);
            q3 = *(const f32x4*)(hp + 24);
        }
        hwA[mt][0][0] = f16x2{ (_Float16)q0[0], (_Float16)q0[1] };
        hwA[mt][0][1] = f16x2{ (_Float16)q0[2], (_Float16)q0[3] };
        hwA[mt][0][2] = f16x2{ (_Float16)q1[0], (_Float16)q1[1] };
        hwA[mt][0][3] = f16x2{ (_Float16)q1[2], (_Float16)q1[3] };
        hwA[mt][1][0] = f16x2{ (_Float16)q2[0], (_Float16)q2[1] };
        hwA[mt][1][1] = f16x2{ (_Float16)q2[2], (_Float16)q2[3] };
        hwA[mt][1][2] = f16x2{ (_Float16)q3[0], (_Float16)q3[1] };
        hwA[mt][1][3] = f16x2{ (_Float16)q3[2], (_Float16)q3[3] };
    }

    f32x16 acc0 = {}, acc1 = {};

    __syncthreads();   // drains chunk-0 stage (vmcnt 0) + hdnT writes

    // ------------- K loop: 16 full chunks (4 k1 each), 2-phase -------------
    for (int c = 0; c < 16; ++c) {
        // stage chunk c+1 into buf (c+1)&1  (chunk 16 is the 2 KB tail)
        {
            int cb  = (c + 1 < 16) ? 8192 : 2048;
            int src = (c + 1) * 8192;
            int bb  = ((c + 1) & 1) * 8192;
            #pragma unroll
            for (int j = 0; j < 2; ++j) {
                int off = wv * 2048 + j * 1024;
                if (off < cb)
                    stage16(wsb + src + off + lane * 16, shb + bb + off);
            }
        }
        // compute chunk c from buf c&1 (LDS only)
        {
            const char* bB = shb + (c & 1) * 8192;
            #pragma unroll
            for (int q = 0; q < 4; ++q) {
                int k1 = c * 4 + q;
                U4 bf0, bf1;
                bf0.u = *(const uint4*)(bB + (2 * q) * 1024 + lane * 16);
                bf1.u = *(const uint4*)(bB + (2 * q + 1) * 1024 + lane * 16);
                u16 t0v = myT[k1 * STRIDE_T + l31];
                u16 t1v = myT[k1 * STRIDE_T + 32 + l31];
                {
                    _Float16 f0 = __builtin_bit_cast(_Float16, t0v);
                    f16x2 hh = { f0, f0 };
                    MT_BODY(acc0, hh, hwA[0], bf0.h, bf1.h);
                }
                {
                    _Float16 f1 = __builtin_bit_cast(_Float16, t1v);
                    f16x2 hh = { f1, f1 };
                    MT_BODY(acc1, hh, hwA[1], bf0.h, bf1.h);
                }
            }
        }
        __syncthreads();
    }
    // ---- tail chunk 16: k1 = 64 (bias row), staged in buf0 ----
    {
        const char* bB = shb;
        U4 bf0, bf1;
        bf0.u = *(const uint4*)(bB + lane * 16);
        bf1.u = *(const uint4*)(bB + 1024 + lane * 16);
        u16 t0v = myT[64 * STRIDE_T + l31];
        u16 t1v = myT[64 * STRIDE_T + 32 + l31];
        {
            _Float16 f0 = __builtin_bit_cast(_Float16, t0v);
            f16x2 hh = { f0, f0 };
            MT_BODY(acc0, hh, hwA[0], bf0.h, bf1.h);
        }
        {
            _Float16 f1 = __builtin_bit_cast(_Float16, t1v);
            f16x2 hh = { f1, f1 };
            MT_BODY(acc1, hh, hwA[1], bf0.h, bf1.h);
        }
    }

    // ---------------- store messages ----------------
    #pragma unroll
    for (int mt = 0; mt < 2; ++mt) {
        #pragma unroll
        for (int r = 0; r < 16; ++r) {
            int row = (r & 3) + 8 * (r >> 2) + 4 * h;
            int e = tileBase + mt * 32 + row;
            float v = (mt == 0) ? acc0[r] : acc1[r];
            if (e < E) out[(size_t)e * 32 + l31] = v;
        }
    }
}

extern "C" void kernel_launch(void* const* d_in, const int* in_sizes, int n_in,
                              void* d_out, int out_size, void* d_ws, size_t ws_size,
                              hipStream_t stream)
{
    // inputs: 0=h_v (unused), 1=h_w, 2=edge_features, 3=W1, 4=b1, 5=W2, 6=b2
    const float* h_w = (const float*)d_in[1];
    const float* ef  = (const float*)d_in[2];
    const float* W1  = (const float*)d_in[3];
    const float* b1  = (const float*)d_in[4];
    const float* W2  = (const float*)d_in[5];
    const float* b2  = (const float*)d_in[6];
    float* out = (float*)d_out;
    const int E = in_sizes[1] / 32;
    u16* ws = (u16*)d_ws;   // needs 135,168 B

    prep_kernel<<<33, 256, 0, stream>>>(W1, W2, b2, ws);

    const int blocks = (E + 4 * 64 - 1) / (4 * 64);
    edge_kernel<<<blocks, 256, 0, stream>>>(h_w, ef, b1, ws, out, E);
}

// Round 4
// 47.246 us; speedup vs baseline: 1.0667x; 1.0667x over previous
//
#include <hip/hip_runtime.h>

typedef unsigned short u16;
typedef _Float16 f16x2 __attribute__((ext_vector_type(2)));
typedef _Float16 f16x8 __attribute__((ext_vector_type(8)));
typedef float    f32x4  __attribute__((ext_vector_type(4)));
typedef float    f32x16 __attribute__((ext_vector_type(16)));

// Fragment k-map convention (same in BOTH operand slots — proven by r1-r3
// validation which used it for A and B simultaneously):
//   k_local(lane, j) = (lane>>5)*4 + (j&3) + 8*(j>>2),  j = 0..7
// D layout (measured m74/m101): col = lane&31 (N), row = (r&3)+8*(r>>2)+4*(lane>>5) (M)

union U4 { uint4 u; f16x8 h; u16 s[8]; };
union HU { f16x2 h2[4]; f16x8 h8; };

// ---------------------------------------------------------------------------
// Prep: Bf = W2flat (2080 x 32, f16) in fragment order (bytes [0, 133120));
// W1f fragments (bytes [133120, 135168)); b1p permuted bias table f32
// (bytes [135168, 135424)): b1p[h][nt][r] = b1[nt*32 + (r&3)+8*(r>>2)+4h].
// ---------------------------------------------------------------------------
__global__ void prep_kernel(const float* __restrict__ W1,
                            const float* __restrict__ b1,
                            const float* __restrict__ W2,
                            const float* __restrict__ b2,
                            u16* __restrict__ ws)
{
    int id = blockIdx.x * 256 + threadIdx.x;
    if (id < 8320) {                       // 130 ksteps * 64 lanes
        int k2 = id >> 6, l = id & 63;
        int h = l >> 5, col = l & 31;
        U4 o;
        #pragma unroll
        for (int g = 0; g < 2; ++g) {
            int base4 = k2 * 16 + g * 8 + h * 4;   // 4-aligned, no 32-straddle
            f32x4 v;
            if (base4 < 2048) {
                int k1 = base4 >> 5, j32 = base4 & 31;
                v = *(const f32x4*)&W2[k1 * 1024 + col * 32 + j32];
            } else {
                v = *(const f32x4*)&b2[col * 32 + (base4 - 2048)];
            }
            #pragma unroll
            for (int j = 0; j < 4; ++j)
                o.h[g * 4 + j] = (_Float16)v[j];
        }
        *(uint4*)(ws + id * 8) = o.u;
    } else if (id < 8448) {                // W1 fragments: 2 ntiles * 64 lanes
        int idx = id - 8320;
        int nt = idx >> 6, l = idx & 63;
        int h = l >> 5, col = nt * 32 + (l & 31);
        U4 o;
        #pragma unroll
        for (int g = 0; g < 2; ++g)
            #pragma unroll
            for (int j = 0; j < 4; ++j) {
                int k = g * 8 + h * 4 + j;
                o.h[g * 4 + j] = (_Float16)W1[k * 64 + col];
            }
        *(uint4*)(ws + id * 8) = o.u;
    } else if (id < 8512) {                // b1p: 2h * 2nt * 16r floats
        int idx = id - 8448;
        int hh = idx >> 5, nt = (idx >> 4) & 1, r = idx & 15;
        int row = (r & 3) + 8 * (r >> 2) + 4 * hh;
        ((float*)(ws + 67584))[idx] = b1[nt * 32 + row];
    }
}

__device__ __forceinline__ void stage16(const void* g, void* l) {
    __builtin_amdgcn_global_load_lds(
        (const __attribute__((address_space(1))) void*)g,
        (__attribute__((address_space(3))) void*)l, 16, 0, 0);
}

// ---------------------------------------------------------------------------
// Main kernel: 4 waves/block, 64 edges/wave. NO hdn LDS: transposed layer-1
// puts hdn[own edge][k1] in registers; shfl_xor(32) + one-time cndmask gives
// each lane all 64 k1 as f16x2 Q[mt][nt][p][hq], statically indexed in a
// fully unrolled K loop. LDS = 32 KB B double-buffer only (chunk = 8 k1);
// stage(c+1) under compute(c), 8 barriers total. k1=64 bias row: hdn==1 ->
// A-frag = hwA directly.
// ---------------------------------------------------------------------------
__global__ __launch_bounds__(256, 3) void edge_kernel(
    const float* __restrict__ h_w,
    const float* __restrict__ ef,
    const u16*  __restrict__ ws,
    float* __restrict__ out,
    int E)
{
    __shared__ alignas(16) u16 shm[16384];   // 32 KB
    const int tid  = threadIdx.x;
    const int lane = tid & 63;
    const int l31  = lane & 31;
    const int h    = lane >> 5;
    const int tileBase = (blockIdx.x * 4 + (tid >> 6)) * 64;
    const char* wsb = (const char*)ws;
    char*       shb = (char*)shm;

    // ---- stage chunk 0 (16 KB = k1 0..7) ----
    #pragma unroll
    for (int j = 0; j < 4; ++j)
        stage16(wsb + j * 4096 + tid * 16, shb + j * 4096 + tid * 16);

    // ---- h_w fragments (issued early; f16, kept in regs) ----
    f16x2 hwA[2][2][4];
    #pragma unroll
    for (int mt = 0; mt < 2; ++mt) {
        int e = tileBase + mt * 32 + l31;
        bool ok = e < E;
        f32x4 q0 = {}, q1 = {}, q2 = {}, q3 = {};
        if (ok) {
            const float* hp = h_w + (size_t)e * 32 + h * 4;
            q0 = *(const f32x4*)(hp);
            q1 = *(const f32x4*)(hp + 8);
            q2 = *(const f32x4*)(hp + 16);
            q3 = *(const f32x4*)(hp + 24);
        }
        hwA[mt][0][0] = f16x2{ (_Float16)q0[0], (_Float16)q0[1] };
        hwA[mt][0][1] = f16x2{ (_Float16)q0[2], (_Float16)q0[3] };
        hwA[mt][0][2] = f16x2{ (_Float16)q1[0], (_Float16)q1[1] };
        hwA[mt][0][3] = f16x2{ (_Float16)q1[2], (_Float16)q1[3] };
        hwA[mt][1][0] = f16x2{ (_Float16)q2[0], (_Float16)q2[1] };
        hwA[mt][1][1] = f16x2{ (_Float16)q2[2], (_Float16)q2[3] };
        hwA[mt][1][2] = f16x2{ (_Float16)q3[0], (_Float16)q3[1] };
        hwA[mt][1][3] = f16x2{ (_Float16)q3[2], (_Float16)q3[3] };
    }

    // ---- layer 1 (transposed): c = mfma(W1f as A, ef as B) ----
    const uint4* W1f = (const uint4*)(ws + 8320 * 8);
    U4 w1f0, w1f1;
    w1f0.u = W1f[lane];
    w1f1.u = W1f[64 + lane];
    const float* b1pf = (const float*)(ws + 67584);
    f32x4 bv[2][4];
    #pragma unroll
    for (int nt = 0; nt < 2; ++nt)
        #pragma unroll
        for (int qr = 0; qr < 4; ++qr)
            bv[nt][qr] = *(const f32x4*)(b1pf + h * 32 + nt * 16 + qr * 4);

    f16x2 Q[2][2][8][2];   // [mt][nt][p][hq]  — all indices compile-time
    #pragma unroll
    for (int mt = 0; mt < 2; ++mt) {
        int e = tileBase + mt * 32 + l31;
        bool ok = e < E;
        f32x4 g0 = {}, g1 = {};
        if (ok) {
            g0 = *(const f32x4*)&ef[e * 16 + h * 4];
            g1 = *(const f32x4*)&ef[e * 16 + 8 + h * 4];
        }
        U4 a;
        #pragma unroll
        for (int j = 0; j < 4; ++j) {
            a.h[j]     = (_Float16)g0[j];
            a.h[4 + j] = (_Float16)g1[j];
        }
        f32x16 c0 = {}, c1 = {};
        c0 = __builtin_amdgcn_mfma_f32_32x32x16_f16(w1f0.h, a.h, c0, 0, 0, 0);
        c1 = __builtin_amdgcn_mfma_f32_32x32x16_f16(w1f1.h, a.h, c1, 0, 0, 0);
        #pragma unroll
        for (int nt = 0; nt < 2; ++nt) {
            #pragma unroll
            for (int p = 0; p < 8; ++p) {
                float r0 = (nt ? c1[2 * p]     : c0[2 * p]);
                float r1 = (nt ? c1[2 * p + 1] : c0[2 * p + 1]);
                float v0 = fmaxf(r0 + bv[nt][p >> 1][(2 * p) & 3],     0.f);
                float v1 = fmaxf(r1 + bv[nt][p >> 1][(2 * p + 1) & 3], 0.f);
                f16x2 own = { (_Float16)v0, (_Float16)v1 };
                unsigned swu = __shfl_xor(__builtin_bit_cast(unsigned, own), 32, 64);
                f16x2 sw = __builtin_bit_cast(f16x2, swu);
                Q[mt][nt][p][0] = h ? sw : own;   // hq = 0 version
                Q[mt][nt][p][1] = h ? own : sw;   // hq = 1 version
            }
        }
    }

    f32x16 acc0 = {}, acc1 = {};
    __syncthreads();   // chunk-0 stage drained

    // ---- K loop: 8 chunks x 8 k1, fully unrolled (static Q indexing) ----
    #pragma unroll
    for (int c = 0; c < 8; ++c) {
        if (c < 7) {                       // stage chunk c+1 (16 KB)
            #pragma unroll
            for (int j = 0; j < 4; ++j)
                stage16(wsb + (c + 1) * 16384 + j * 4096 + tid * 16,
                        shb + ((c + 1) & 1) * 16384 + j * 4096 + tid * 16);
        } else {                           // stage tail (2 KB, ksteps 128-129) into buf0
            if (tid < 128)
                stage16(wsb + 131072 + tid * 16, shb + tid * 16);
        }
        const char* bB = shb + (c & 1) * 16384;
        #pragma unroll
        for (int qq = 0; qq < 8; ++qq) {
            const int k1   = c * 8 + qq;
            const int nt   = k1 >> 5;
            const int q    = k1 & 31;
            const int pa   = ((q & 3) >> 1) + 2 * (q >> 3);
            const int half = q & 1;
            const int hq   = (q >> 2) & 1;
            U4 bf0, bf1;
            bf0.u = *(const uint4*)(bB + (2 * qq) * 1024 + lane * 16);
            bf1.u = *(const uint4*)(bB + (2 * qq + 1) * 1024 + lane * 16);
            _Float16 x0 = Q[0][nt][pa][hq][half];
            _Float16 x1 = Q[1][nt][pa][hq][half];
            f16x2 hh0 = { x0, x0 }, hh1 = { x1, x1 };
            HU A0, A1;
            #pragma unroll
            for (int rr = 0; rr < 4; ++rr) { A0.h2[rr] = hh0 * hwA[0][0][rr]; A1.h2[rr] = hh1 * hwA[1][0][rr]; }
            acc0 = __builtin_amdgcn_mfma_f32_32x32x16_f16(A0.h8, bf0.h, acc0, 0, 0, 0);
            acc1 = __builtin_amdgcn_mfma_f32_32x32x16_f16(A1.h8, bf0.h, acc1, 0, 0, 0);
            #pragma unroll
            for (int rr = 0; rr < 4; ++rr) { A0.h2[rr] = hh0 * hwA[0][1][rr]; A1.h2[rr] = hh1 * hwA[1][1][rr]; }
            acc0 = __builtin_amdgcn_mfma_f32_32x32x16_f16(A0.h8, bf1.h, acc0, 0, 0, 0);
            acc1 = __builtin_amdgcn_mfma_f32_32x32x16_f16(A1.h8, bf1.h, acc1, 0, 0, 0);
        }
        __syncthreads();
    }

    // ---- tail k1 = 64 (hdn == 1): A-frag = hwA directly, B in buf0 ----
    {
        U4 bf0, bf1;
        bf0.u = *(const uint4*)(shb + lane * 16);
        bf1.u = *(const uint4*)(shb + 1024 + lane * 16);
        HU A0, A1;
        #pragma unroll
        for (int rr = 0; rr < 4; ++rr) { A0.h2[rr] = hwA[0][0][rr]; A1.h2[rr] = hwA[1][0][rr]; }
        acc0 = __builtin_amdgcn_mfma_f32_32x32x16_f16(A0.h8, bf0.h, acc0, 0, 0, 0);
        acc1 = __builtin_amdgcn_mfma_f32_32x32x16_f16(A1.h8, bf0.h, acc1, 0, 0, 0);
        #pragma unroll
        for (int rr = 0; rr < 4; ++rr) { A0.h2[rr] = hwA[0][1][rr]; A1.h2[rr] = hwA[1][1][rr]; }
        acc0 = __builtin_amdgcn_mfma_f32_32x32x16_f16(A0.h8, bf1.h, acc0, 0, 0, 0);
        acc1 = __builtin_amdgcn_mfma_f32_32x32x16_f16(A1.h8, bf1.h, acc1, 0, 0, 0);
    }

    // ---- store messages ----
    #pragma unroll
    for (int mt = 0; mt < 2; ++mt) {
        #pragma unroll
        for (int r = 0; r < 16; ++r) {
            int row = (r & 3) + 8 * (r >> 2) + 4 * h;
            int e = tileBase + mt * 32 + row;
            float v = (mt == 0) ? acc0[r] : acc1[r];
            if (e < E) out[(size_t)e * 32 + l31] = v;
        }
    }
}

extern "C" void kernel_launch(void* const* d_in, const int* in_sizes, int n_in,
                              void* d_out, int out_size, void* d_ws, size_t ws_size,
                              hipStream_t stream)
{
    // inputs: 0=h_v (unused), 1=h_w, 2=edge_features, 3=W1, 4=b1, 5=W2, 6=b2
    const float* h_w = (const float*)d_in[1];
    const float* ef  = (const float*)d_in[2];
    const float* W1  = (const float*)d_in[3];
    const float* b1  = (const float*)d_in[4];
    const float* W2  = (const float*)d_in[5];
    const float* b2  = (const float*)d_in[6];
    float* out = (float*)d_out;
    const int E = in_sizes[1] / 32;
    u16* ws = (u16*)d_ws;   // needs 135,424 B

    prep_kernel<<<34, 256, 0, stream>>>(W1, b1, W2, b2, ws);

    const int blocks = (E + 255) / 256;
    edge_kernel<<<blocks, 256, 0, stream>>>(h_w, ef, ws, out, E);
}